// Round 1
// baseline (9821.519 us; speedup 1.0000x reference)
//
#include <hip/hip_runtime.h>

// ---------------------------------------------------------------------------
// Seq2seq LSTM (B=256, S=336, F=8, H=512, P=96) on MI355X.
// Persistent cooperative kernel: 256 blocks = 16 batch-groups x 16 unit-groups.
// Weights live in VGPRs (MFMA-fragment-packed f16), h exchanged via global
// memory with per-(step, batch-group) release/acquire counters.
// ---------------------------------------------------------------------------

typedef _Float16 half8 __attribute__((ext_vector_type(8)));
typedef float f32x4 __attribute__((ext_vector_type(4)));

#define B_SZ 256
#define S_LEN 336
#define P_LEN 96
#define H_SZ 512
#define T_TOT (S_LEN + P_LEN)   // 432

// workspace layout (bytes)
#define SZ_PACK (16*8*17*64*8*2)          // 2,228,224: packed weights (one phase)
#define OFF_PACK_ENC 0
#define OFF_PACK_DEC (SZ_PACK)
#define OFF_HBUF (2*SZ_PACK)
#define SZ_HBUF (2*B_SZ*H_SZ*2)           // double-buffered h, f16
#define OFF_YBUF (OFF_HBUF + SZ_HBUF)
#define SZ_YBUF (P_LEN*B_SZ*4)            // y partial sums, fp32
#define OFF_CNT (OFF_YBUF + SZ_YBUF)
#define SZ_CNT (T_TOT*16*4)               // per-(t, bg) arrival counters

__device__ __forceinline__ float sigf(float x){
  return __builtin_amdgcn_rcpf(1.f + __expf(-x));
}
__device__ __forceinline__ float tanh_fast(float x){
  return 2.f*__builtin_amdgcn_rcpf(1.f + __expf(-2.f*x)) - 1.f;
}

// Pack Whh (+ folded Wih) into MFMA B-fragment order, f16.
// Fragment k = s*32 + (lane>>4)*8 + j ; col = lane&15 -> gate row.
// k in [512,520) holds enc_Wih columns (encoder) or dec_Wih at k==512 (decoder).
__global__ void pack_weights(const float* __restrict__ Whh,
                             const float* __restrict__ Wih,
                             _Float16* __restrict__ dst, int isDec){
  int lane = threadIdx.x;
  int s = blockIdx.x, w = blockIdx.y, og = blockIdx.z;
  int col16 = lane & 15, hi = lane >> 4;
  int gatei = col16 >> 2, uloc = col16 & 3;
  int grow = gatei*H_SZ + og*32 + w*4 + uloc;   // row of the (2048 x 512) weight
  half8 v;
  #pragma unroll
  for (int j = 0; j < 8; j++){
    int k = s*32 + hi*8 + j;
    float x = 0.f;
    if (k < H_SZ)                      x = Whh[(size_t)grow*H_SZ + k];
    else if (!isDec && k < H_SZ + 8)   x = Wih[(size_t)grow*8 + (k - H_SZ)];
    else if (isDec && k == H_SZ)       x = Wih[grow];
    v[j] = (_Float16)x;
  }
  *(half8*)(dst + ((size_t)(((og*8 + w)*17 + s)*64 + lane))*8) = v;
}

__global__ void finalize_out(const float* __restrict__ y_buf,
                             const float* __restrict__ lin_b,
                             float* __restrict__ out){
  int i = blockIdx.x*256 + threadIdx.x;        // i = b*96 + td
  int b = i / P_LEN, td = i % P_LEN;
  out[i] = y_buf[td*B_SZ + b] + lin_b[0];
}

__global__ __launch_bounds__(512) void lstm_main(
    const float* __restrict__ x_enc, const float* __restrict__ enc_b,
    const float* __restrict__ dec_b, const float* __restrict__ lin_W,
    const float* __restrict__ lin_b,
    const _Float16* __restrict__ packEnc, const _Float16* __restrict__ packDec,
    _Float16* __restrict__ h_buf, float* __restrict__ y_buf,
    unsigned int* __restrict__ cnt)
{
  const int bx = blockIdx.x;
  const int og = bx >> 4, bg = bx & 15;     // bg in low bits -> bg-group on one XCD
  const int tid = threadIdx.x;
  const int w = tid >> 6, lane = tid & 63;
  const int col16 = lane & 15, hi = lane >> 4;
  const int gatei = col16 >> 2;             // 0:i 1:f 2:g 3:o
  const int unit = og*32 + w*4 + (col16 & 3);
  const int grow = gatei*H_SZ + unit;
  const int r0 = bg*16;                     // base batch row

  // A-tile: 16 rows x 1152B (512 h-f16 + 64B x/y tail), XOR-swizzled (bits 4-6)
  __shared__ __align__(16) unsigned char Abuf[16*1152];

  // Weight slice in registers: 17 K-frags of half8 (68 VGPRs)
  half8 Breg[17];
  #pragma unroll
  for (int s = 0; s < 17; s++)
    Breg[s] = *(const half8*)(packEnc + ((size_t)(((og*8 + w)*17 + s)*64 + lane))*8);
  float bias = enc_b[grow];
  const float linw = lin_W[unit];
  const float lbv  = lin_b[0];
  float c4[4] = {0.f, 0.f, 0.f, 0.f};      // cell state, resident all 432 steps

  const int str_r = tid >> 5, str_c = tid & 31;  // h-staging role
  const int abase = col16*1152;                  // A-frag row = lane&15
  const int asw   = (col16 & 7) << 4;

  for (int t = 0; t < T_TOT; t++){
    const bool isDec = (t >= S_LEN);
    if (t == S_LEN){                        // switch to decoder weights/bias
      #pragma unroll
      for (int s = 0; s < 17; s++)
        Breg[s] = *(const half8*)(packDec + ((size_t)(((og*8 + w)*17 + s)*64 + lane))*8);
      bias = dec_b[grow];
    }

    if (t > 0){
      if (tid == 0){
        while (__hip_atomic_load(&cnt[(t-1)*16 + bg], __ATOMIC_RELAXED,
                                 __HIP_MEMORY_SCOPE_AGENT) != 16u) {}
      }
      __syncthreads();
      __builtin_amdgcn_fence(__ATOMIC_ACQUIRE, "agent");
      // stage h_{t-1} (16 rows x 512 f16) into LDS, swizzled
      const _Float16* hsrc = h_buf
          + ((size_t)(((t-1)&1)*B_SZ + r0 + str_r))*H_SZ + str_c*16;
      uint4 v0 = *(const uint4*)(hsrc);
      uint4 v1 = *(const uint4*)(hsrc + 8);
      const int sw = (str_r & 7) << 4;
      *(uint4*)&Abuf[str_r*1152 + ((str_c*32     ) ^ sw)] = v0;
      *(uint4*)&Abuf[str_r*1152 + ((str_c*32 + 16) ^ sw)] = v1;
    }

    // stage x_t (encoder) or y_{t-1} (decoder) into the K=512.. tail; zero rest
    if (!isDec){
      if (tid < 128){
        int r = tid >> 3, f = tid & 7;
        float xv = x_enc[(size_t)(r0 + r)*(S_LEN*8) + t*8 + f];
        *(_Float16*)&Abuf[r*1152 + 1024 + ((r & 7) << 4) + f*2] = (_Float16)xv;
      } else if (tid < 176){
        int idx = tid - 128;
        int r = idx & 15, u = (idx >> 4) + 1;      // zero hi=1..3 slots (NaN guard)
        uint4 z = {0, 0, 0, 0};
        *(uint4*)&Abuf[r*1152 + ((1024 + u*16) ^ ((r & 7) << 4))] = z;
      }
    } else {
      if (tid < 64){
        int r = tid & 15, u = tid >> 4;
        if (u == 0){
          float yv;
          if (t == S_LEN) yv = x_enc[(size_t)(r0 + r)*(S_LEN*8) + 335*8 + 3];
          else            yv = y_buf[(t-1-S_LEN)*B_SZ + r0 + r] + lbv;
          half8 va;
          #pragma unroll
          for (int q = 0; q < 8; q++) va[q] = (_Float16)0.f;
          va[0] = (_Float16)yv;
          *(half8*)&Abuf[r*1152 + (1024 ^ ((r & 7) << 4))] = va;
        } else {
          uint4 z = {0, 0, 0, 0};
          *(uint4*)&Abuf[r*1152 + ((1024 + u*16) ^ ((r & 7) << 4))] = z;
        }
      }
    }
    __syncthreads();

    // gates = bias + [h | x] @ [Whh | Wih]^T  (17 K-steps of 16x16x32 f16 MFMA)
    f32x4 acc = {bias, bias, bias, bias};
    if (t == 0){   // h0 = 0: only the x K-tile contributes
      half8 a = *(const half8*)&Abuf[abase + ((1024 + hi*16) ^ asw)];
      acc = __builtin_amdgcn_mfma_f32_16x16x32_f16(a, Breg[16], acc, 0, 0, 0);
    } else {
      #pragma unroll
      for (int s = 0; s < 17; s++){
        half8 a = *(const half8*)&Abuf[abase + ((s*64 + hi*16) ^ asw)];
        acc = __builtin_amdgcn_mfma_f32_16x16x32_f16(a, Breg[s], acc, 0, 0, 0);
      }
    }

    // LSTM pointwise: gather i,f,g,o across lanes c, c^4, c^8, c^12
    float hold[4];
    #pragma unroll
    for (int j = 0; j < 4; j++){
      float a   = acc[j];
      float x4  = __shfl_xor(a, 4);
      float x8  = __shfl_xor(a, 8);
      float x12 = __shfl_xor(x4, 8);
      float gi, gf, gg, go;
      if      (gatei == 0){ gi = a;   gf = x4;  gg = x8;  go = x12; }
      else if (gatei == 1){ gi = x4;  gf = a;   gg = x12; go = x8;  }
      else if (gatei == 2){ gi = x8;  gf = x12; gg = a;   go = x4;  }
      else                { gi = x12; gf = x8;  gg = x4;  go = a;   }
      float cn = sigf(gf)*c4[j] + sigf(gi)*tanh_fast(gg);
      c4[j] = cn;
      hold[j] = sigf(go)*tanh_fast(cn);
    }

    // write h slice (gate-0 lanes own unit = og*32 + w*4 + col16)
    if (gatei == 0){
      _Float16* hdst = h_buf + ((size_t)((t&1)*B_SZ + r0 + hi*4))*H_SZ + unit;
      #pragma unroll
      for (int j = 0; j < 4; j++) hdst[(size_t)j*H_SZ] = (_Float16)hold[j];
    }

    // decoder: accumulate y partials (sum over this wave's 4 units)
    if (isDec){
      #pragma unroll
      for (int j = 0; j < 4; j++){
        float pv = (gatei == 0) ? hold[j]*linw : 0.f;
        pv += __shfl_xor(pv, 1);
        pv += __shfl_xor(pv, 2);
        if (col16 == 0)
          __hip_atomic_fetch_add(&y_buf[(t-S_LEN)*B_SZ + r0 + hi*4 + j], pv,
                                 __ATOMIC_RELAXED, __HIP_MEMORY_SCOPE_AGENT);
      }
    }

    __syncthreads();   // drains vmcnt: all h stores + y atomics issued
    if (tid == 0)
      __hip_atomic_fetch_add(&cnt[t*16 + bg], 1u,
                             __ATOMIC_RELEASE, __HIP_MEMORY_SCOPE_AGENT);
  }
}

extern "C" void kernel_launch(void* const* d_in, const int* in_sizes, int n_in,
                              void* d_out, int out_size, void* d_ws, size_t ws_size,
                              hipStream_t stream) {
  const float* x_enc   = (const float*)d_in[0];
  const float* enc_Wih = (const float*)d_in[1];
  const float* enc_Whh = (const float*)d_in[2];
  const float* enc_b   = (const float*)d_in[3];
  const float* dec_Wih = (const float*)d_in[4];
  const float* dec_Whh = (const float*)d_in[5];
  const float* dec_b   = (const float*)d_in[6];
  const float* lin_W   = (const float*)d_in[7];
  const float* lin_b   = (const float*)d_in[8];

  char* ws = (char*)d_ws;
  _Float16* packEnc = (_Float16*)(ws + OFF_PACK_ENC);
  _Float16* packDec = (_Float16*)(ws + OFF_PACK_DEC);
  _Float16* h_buf   = (_Float16*)(ws + OFF_HBUF);
  float*    y_buf   = (float*)(ws + OFF_YBUF);
  unsigned int* cnt = (unsigned int*)(ws + OFF_CNT);

  // zero y partials + arrival counters (stateless across replays)
  hipMemsetAsync(ws + OFF_YBUF, 0, SZ_YBUF + SZ_CNT, stream);

  pack_weights<<<dim3(17, 8, 16), 64, 0, stream>>>(enc_Whh, enc_Wih, packEnc, 0);
  pack_weights<<<dim3(17, 8, 16), 64, 0, stream>>>(dec_Whh, dec_Wih, packDec, 1);

  void* args[] = { (void*)&x_enc, (void*)&enc_b, (void*)&dec_b, (void*)&lin_W,
                   (void*)&lin_b, (void*)&packEnc, (void*)&packDec,
                   (void*)&h_buf, (void*)&y_buf, (void*)&cnt };
  hipLaunchCooperativeKernel((void*)lstm_main, dim3(256), dim3(512),
                             args, 0, stream);

  finalize_out<<<dim3((B_SZ*P_LEN)/256), 256, 0, stream>>>(y_buf, lin_b, (float*)d_out);
}

// Round 2
// 1742.225 us; speedup vs baseline: 5.6373x; 5.6373x over previous
//
#include <hip/hip_runtime.h>

// ---------------------------------------------------------------------------
// Seq2seq LSTM (B=256, S=336, F=8, H=512, P=96) on MI355X.
// Persistent cooperative kernel: 256 blocks = 16 batch-groups x 16 unit-groups.
// Weights live in VGPRs (MFMA-fragment-packed f16). h is exchanged through the
// Infinity Cache with RELAXED agent-scope atomics (sc0/sc1 — no L2 wb/inv!),
// ordered by vmcnt drains + per-(t,bg) arrival counters.
// ---------------------------------------------------------------------------

typedef _Float16 half8 __attribute__((ext_vector_type(8)));
typedef float f32x4 __attribute__((ext_vector_type(4)));
typedef unsigned long long ull;

#define B_SZ 256
#define S_LEN 336
#define P_LEN 96
#define H_SZ 512
#define T_TOT (S_LEN + P_LEN)   // 432

// workspace layout (bytes)
#define SZ_PACK (16*8*17*64*8*2)          // 2,228,224: packed weights (one phase)
#define OFF_PACK_ENC 0
#define OFF_PACK_DEC (SZ_PACK)
#define OFF_HBUF (2*SZ_PACK)
#define SZ_HBUF (2*B_SZ*H_SZ*2)           // double-buffered h, f16
#define OFF_YBUF (OFF_HBUF + SZ_HBUF)
#define SZ_YBUF (P_LEN*B_SZ*4)            // y partial sums, fp32
#define OFF_CNT (OFF_YBUF + SZ_YBUF)
#define SZ_CNT (T_TOT*16*4)               // per-(t, bg) arrival counters

__device__ __forceinline__ float sigf(float x){
  return __builtin_amdgcn_rcpf(1.f + __expf(-x));
}
__device__ __forceinline__ float tanh_fast(float x){
  return 2.f*__builtin_amdgcn_rcpf(1.f + __expf(-2.f*x)) - 1.f;
}

// Pack Whh (+ folded Wih) into MFMA B-fragment order, f16.
// Fragment k = s*32 + (lane>>4)*8 + j ; col = lane&15 -> gate row.
// k in [512,520) holds enc_Wih columns (encoder) or dec_Wih at k==512 (decoder).
__global__ void pack_weights(const float* __restrict__ Whh,
                             const float* __restrict__ Wih,
                             _Float16* __restrict__ dst, int isDec){
  int lane = threadIdx.x;
  int s = blockIdx.x, w = blockIdx.y, og = blockIdx.z;
  int col16 = lane & 15, hi = lane >> 4;
  int gatei = col16 >> 2, uloc = col16 & 3;
  int grow = gatei*H_SZ + og*32 + w*4 + uloc;   // row of the (2048 x 512) weight
  half8 v;
  #pragma unroll
  for (int j = 0; j < 8; j++){
    int k = s*32 + hi*8 + j;
    float x = 0.f;
    if (k < H_SZ)                      x = Whh[(size_t)grow*H_SZ + k];
    else if (!isDec && k < H_SZ + 8)   x = Wih[(size_t)grow*8 + (k - H_SZ)];
    else if (isDec && k == H_SZ)       x = Wih[grow];
    v[j] = (_Float16)x;
  }
  *(half8*)(dst + ((size_t)(((og*8 + w)*17 + s)*64 + lane))*8) = v;
}

__global__ void finalize_out(const float* __restrict__ y_buf,
                             const float* __restrict__ lin_b,
                             float* __restrict__ out){
  int i = blockIdx.x*256 + threadIdx.x;        // i = b*96 + td
  int b = i / P_LEN, td = i % P_LEN;
  out[i] = y_buf[td*B_SZ + b] + lin_b[0];
}

#define AFRAG(s) (*(const half8*)&Abuf[abase + (((s)*64 + hi*16) ^ asw)])

__global__ __launch_bounds__(512) void lstm_main(
    const float* __restrict__ x_enc, const float* __restrict__ enc_b,
    const float* __restrict__ dec_b, const float* __restrict__ lin_W,
    const float* __restrict__ lin_b,
    const _Float16* __restrict__ packEnc, const _Float16* __restrict__ packDec,
    ull* __restrict__ h_buf,                // [2][256 rows][128 ull] (f16 x4)
    float* __restrict__ y_buf,
    unsigned int* __restrict__ cnt)
{
  const int bx = blockIdx.x;
  const int og = bx >> 4, bg = bx & 15;     // bg = bx&15 -> a bg's 16 blocks share bx%8 (same XCD under round-robin)
  const int tid = threadIdx.x;
  const int w = tid >> 6, lane = tid & 63;
  const int col16 = lane & 15, hi = lane >> 4;
  const int gatei = col16 >> 2;             // 0:i 1:f 2:g 3:o
  const int q4 = col16 & 3;
  const int unit = og*32 + w*4 + q4;
  const int grow = gatei*H_SZ + unit;
  const int r0 = bg*16;                     // base batch row

  // A-tile: 16 rows x 1152B (512 h-f16 + x/y tail), XOR-swizzled (bits 4-6)
  __shared__ __align__(16) unsigned char Abuf[16*1152];
  __shared__ float yred[8][16];             // per-wave y partials (decoder)

  // Weight slice in registers: 17 K-frags of half8 (68 VGPRs)
  half8 Breg[17];
  #pragma unroll
  for (int s = 0; s < 17; s++)
    Breg[s] = *(const half8*)(packEnc + ((size_t)(((og*8 + w)*17 + s)*64 + lane))*8);
  float bias = enc_b[grow];
  const float linw = lin_W[unit];
  const float lbv  = lin_b[0];
  float c4[4] = {0.f, 0.f, 0.f, 0.f};      // cell state, resident all 432 steps

  const int srow = tid >> 5, sseg = tid & 31;    // h-staging role (16 rows x 32 segs)
  const int ssw  = (srow & 7) << 4;
  const int abase = col16*1152;                  // A-frag row = lane&15
  const int asw   = (col16 & 7) << 4;

  for (int t = 0; t < T_TOT; t++){
    const bool isDec = (t >= S_LEN);
    if (t == S_LEN){                        // switch to decoder weights/bias (flag-independent)
      #pragma unroll
      for (int s = 0; s < 17; s++)
        Breg[s] = *(const half8*)(packDec + ((size_t)(((og*8 + w)*17 + s)*64 + lane))*8);
      bias = dec_b[grow];
    }

    // issue x load early (read-only, independent of the flag -> hides HBM latency)
    float xv = 0.f;
    if (!isDec && tid < 128)
      xv = x_enc[(size_t)(r0 + (tid >> 3))*(S_LEN*8) + t*8 + (tid & 7)];

    if (t > 0){
      if (tid == 0){
        while (__hip_atomic_load(&cnt[(t-1)*16 + bg], __ATOMIC_RELAXED,
                                 __HIP_MEMORY_SCOPE_AGENT) != 16u) {}
      }
      __syncthreads();   // broadcast flag; also separates prev MFMA reads from Abuf writes
      // stage h_{t-1}: coalesced 8B LLC loads -> swizzled b128 LDS writes
      const ull* hs = h_buf + ((size_t)(((t-1)&1)*B_SZ + r0 + srow))*128 + sseg*4;
      ull d0 = __hip_atomic_load(hs+0, __ATOMIC_RELAXED, __HIP_MEMORY_SCOPE_AGENT);
      ull d1 = __hip_atomic_load(hs+1, __ATOMIC_RELAXED, __HIP_MEMORY_SCOPE_AGENT);
      ull d2 = __hip_atomic_load(hs+2, __ATOMIC_RELAXED, __HIP_MEMORY_SCOPE_AGENT);
      ull d3 = __hip_atomic_load(hs+3, __ATOMIC_RELAXED, __HIP_MEMORY_SCOPE_AGENT);
      uint4 A;  A.x = (unsigned)d0; A.y = (unsigned)(d0>>32);
                A.z = (unsigned)d1; A.w = (unsigned)(d1>>32);
      uint4 Bv; Bv.x = (unsigned)d2; Bv.y = (unsigned)(d2>>32);
                Bv.z = (unsigned)d3; Bv.w = (unsigned)(d3>>32);
      *(uint4*)&Abuf[srow*1152 + ((sseg*32     ) ^ ssw)] = A;
      *(uint4*)&Abuf[srow*1152 + ((sseg*32 + 16) ^ ssw)] = Bv;
    }

    // stage x_t (encoder) or y_{t-1} (decoder) into the K=512.. tail
    if (!isDec){
      if (tid < 128){
        int r = tid >> 3, f = tid & 7;
        *(_Float16*)&Abuf[r*1152 + (1024 ^ ((r & 7) << 4)) + f*2] = (_Float16)xv;
      } else if (t == 0 && tid < 176){
        int idx = tid - 128;                 // zero k=520..543 slots ONCE (persist)
        int r = idx & 15, u = (idx >> 4) + 1;
        uint4 z = {0, 0, 0, 0};
        *(uint4*)&Abuf[r*1152 + ((1024 + u*16) ^ ((r & 7) << 4))] = z;
      }
    } else {
      if (tid < 16){
        int r = tid;
        float yv;
        if (t == S_LEN) yv = x_enc[(size_t)(r0 + r)*(S_LEN*8) + 335*8 + 3];
        else yv = __hip_atomic_load(&y_buf[(t-1-S_LEN)*B_SZ + r0 + r],
                                    __ATOMIC_RELAXED, __HIP_MEMORY_SCOPE_AGENT) + lbv;
        half8 va;
        #pragma unroll
        for (int q = 0; q < 8; q++) va[q] = (_Float16)0.f;
        va[0] = (_Float16)yv;
        *(half8*)&Abuf[r*1152 + (1024 ^ ((r & 7) << 4))] = va;
      }
    }
    __syncthreads();

    // gates = bias + [h | x] @ [Whh | Wih]^T  (17 K-frags, 2 MFMA dep-chains)
    f32x4 acc = {bias, bias, bias, bias};
    if (t == 0){   // h0 = 0: only the x K-tile contributes
      half8 a = AFRAG(16);
      acc = __builtin_amdgcn_mfma_f32_16x16x32_f16(a, Breg[16], acc, 0, 0, 0);
    } else {
      f32x4 acc1 = {0.f, 0.f, 0.f, 0.f};
      #pragma unroll
      for (int s = 0; s < 16; s += 2){
        half8 a0 = AFRAG(s), a1 = AFRAG(s+1);
        acc  = __builtin_amdgcn_mfma_f32_16x16x32_f16(a0, Breg[s],   acc,  0, 0, 0);
        acc1 = __builtin_amdgcn_mfma_f32_16x16x32_f16(a1, Breg[s+1], acc1, 0, 0, 0);
      }
      half8 a16 = AFRAG(16);
      acc = __builtin_amdgcn_mfma_f32_16x16x32_f16(a16, Breg[16], acc, 0, 0, 0);
      acc = acc + acc1;
    }

    // LSTM pointwise: gather i,f,g,o across lanes c, c^4, c^8, c^12
    float hold[4];
    #pragma unroll
    for (int j = 0; j < 4; j++){
      float a   = acc[j];
      float x4  = __shfl_xor(a, 4);
      float x8  = __shfl_xor(a, 8);
      float x12 = __shfl_xor(x4, 8);
      float gi, gf, gg, go;
      if      (gatei == 0){ gi = a;   gf = x4;  gg = x8;  go = x12; }
      else if (gatei == 1){ gi = x4;  gf = a;   gg = x12; go = x8;  }
      else if (gatei == 2){ gi = x8;  gf = x12; gg = a;   go = x4;  }
      else                { gi = x12; gf = x8;  gg = x4;  go = a;   }
      float cn = sigf(gf)*c4[j] + sigf(gi)*tanh_fast(gg);
      c4[j] = cn;
      hold[j] = sigf(go)*tanh_fast(cn);
    }

    // 4x4 lane transpose within each col16-quad: lane q ends with row hi*4+q,
    // units [og*32+w*4 .. +4) packed as one ull -> single 8B LLC store.
    unsigned short s16[4];
    #pragma unroll
    for (int j = 0; j < 4; j++)
      s16[j] = __builtin_bit_cast(unsigned short, (_Float16)hold[j]);
    unsigned lo01 = (unsigned)s16[0] | ((unsigned)s16[1] << 16);
    unsigned hi23 = (unsigned)s16[2] | ((unsigned)s16[3] << 16);
    const bool qlow = (q4 < 2), up = (q4 & 1);
    unsigned sendA = qlow ? hi23 : lo01;
    unsigned rA    = (unsigned)__shfl_xor((int)sendA, 2);
    unsigned keepA = qlow ? lo01 : hi23;
    unsigned vq_p  = up ? (keepA & 0xffffu) : (keepA >> 16);
    unsigned vqx_p = up ? (rA    & 0xffffu) : (rA    >> 16);
    unsigned sendB = qlow ? (vq_p | (vqx_p << 16)) : (vqx_p | (vq_p << 16));
    unsigned rB    = (unsigned)__shfl_xor((int)sendB, 1);
    unsigned vq_m  = up ? (keepA >> 16) : (keepA & 0xffffu);
    unsigned vqx_m = up ? (rA    >> 16) : (rA    & 0xffffu);
    unsigned ownB  = qlow ? (vq_m | (vqx_m << 16)) : (vqx_m | (vq_m << 16));
    unsigned w0 = up ? ((rB & 0xffffu) | (ownB << 16)) : ((ownB & 0xffffu) | (rB << 16));
    unsigned w1 = up ? ((rB >> 16) | (ownB & 0xffff0000u))
                     : ((ownB >> 16) | (rB & 0xffff0000u));
    if (gatei == 0){
      ull hv = (ull)w0 | ((ull)w1 << 32);
      int row = hi*4 + q4;
      __hip_atomic_store(h_buf + ((size_t)((t&1)*B_SZ + r0 + row))*128 + og*8 + w,
                         hv, __ATOMIC_RELAXED, __HIP_MEMORY_SCOPE_AGENT);
    }

    // decoder: per-wave y partials into LDS (one LLC atomic per row per block)
    if (isDec){
      #pragma unroll
      for (int j = 0; j < 4; j++){
        float pv = (gatei == 0) ? hold[j]*linw : 0.f;
        pv += __shfl_xor(pv, 1);
        pv += __shfl_xor(pv, 2);
        if (col16 == 0) yred[w][hi*4 + j] = pv;
      }
    }

    asm volatile("s_waitcnt vmcnt(0)" ::: "memory");  // h stores visible at LLC
    __syncthreads();

    if (isDec && tid < 16){
      float sy = 0.f;
      #pragma unroll
      for (int ww = 0; ww < 8; ww++) sy += yred[ww][tid];
      __hip_atomic_fetch_add(&y_buf[(t-S_LEN)*B_SZ + r0 + tid], sy,
                             __ATOMIC_RELAXED, __HIP_MEMORY_SCOPE_AGENT);
    }
    if (tid == 0){
      asm volatile("s_waitcnt vmcnt(0)" ::: "memory"); // wave0's y-adds drained
      __hip_atomic_fetch_add(&cnt[t*16 + bg], 1u,
                             __ATOMIC_RELAXED, __HIP_MEMORY_SCOPE_AGENT);
    }
  }
}

extern "C" void kernel_launch(void* const* d_in, const int* in_sizes, int n_in,
                              void* d_out, int out_size, void* d_ws, size_t ws_size,
                              hipStream_t stream) {
  const float* x_enc   = (const float*)d_in[0];
  const float* enc_Wih = (const float*)d_in[1];
  const float* enc_Whh = (const float*)d_in[2];
  const float* enc_b   = (const float*)d_in[3];
  const float* dec_Wih = (const float*)d_in[4];
  const float* dec_Whh = (const float*)d_in[5];
  const float* dec_b   = (const float*)d_in[6];
  const float* lin_W   = (const float*)d_in[7];
  const float* lin_b   = (const float*)d_in[8];

  char* ws = (char*)d_ws;
  _Float16* packEnc = (_Float16*)(ws + OFF_PACK_ENC);
  _Float16* packDec = (_Float16*)(ws + OFF_PACK_DEC);
  ull*      h_buf   = (ull*)(ws + OFF_HBUF);
  float*    y_buf   = (float*)(ws + OFF_YBUF);
  unsigned int* cnt = (unsigned int*)(ws + OFF_CNT);

  // zero y partials + arrival counters (stateless across replays)
  hipMemsetAsync(ws + OFF_YBUF, 0, SZ_YBUF + SZ_CNT, stream);

  pack_weights<<<dim3(17, 8, 16), 64, 0, stream>>>(enc_Whh, enc_Wih, packEnc, 0);
  pack_weights<<<dim3(17, 8, 16), 64, 0, stream>>>(dec_Whh, dec_Wih, packDec, 1);

  void* args[] = { (void*)&x_enc, (void*)&enc_b, (void*)&dec_b, (void*)&lin_W,
                   (void*)&lin_b, (void*)&packEnc, (void*)&packDec,
                   (void*)&h_buf, (void*)&y_buf, (void*)&cnt };
  hipLaunchCooperativeKernel((void*)lstm_main, dim3(256), dim3(512),
                             args, 0, stream);

  finalize_out<<<dim3((B_SZ*P_LEN)/256), 256, 0, stream>>>(y_buf, lin_b, (float*)d_out);
}